// Round 1
// 478.997 us; speedup vs baseline: 1.0898x; 1.0898x over previous
//
#include <hip/hip_runtime.h>
#include <hip/hip_bf16.h>
#include <stdint.h>

#define NN 512
#define HD 128

typedef __attribute__((ext_vector_type(8))) short bf16x8;
typedef __attribute__((ext_vector_type(4))) float f32x4;

static __device__ __forceinline__ float bf2f(unsigned short u) {
  union { uint32_t u32; float f; } cv; cv.u32 = ((uint32_t)u) << 16; return cv.f;
}
static __device__ __forceinline__ unsigned short f2bf(float f) {
  union { float f; uint32_t u; } cv; cv.f = f;
  return (unsigned short)((cv.u + 0x7FFFu + ((cv.u >> 16) & 1u)) >> 16);
}

struct DetectArgs { const uint16_t* p[10]; int n[10]; };

// Per-tensor dtype sniffing (flags[ti]=1 -> fp32, 0 -> bf16). One block per
// tensor so the latency-bound scans run in parallel.
__global__ __launch_bounds__(256) void detect_kernel(DetectArgs a, int* __restrict__ flags) {
  __shared__ int acc[256];
  const int ti = blockIdx.x;
  int n = a.n[ti]; if (n > 2048) n = 2048;
  int g = 0;
  for (int w = threadIdx.x; w < n; w += 256) {
    uint16_t v = a.p[ti][w];
    int e = (v >> 7) & 0xFF;
    g += (v == 0u || (e >= 90 && e <= 133)) ? 1 : 0;
  }
  acc[threadIdx.x] = g;
  __syncthreads();
  for (int s = 128; s > 0; s >>= 1) {
    if (threadIdx.x < s) acc[threadIdx.x] += acc[threadIdx.x + s];
    __syncthreads();
  }
  if (threadIdx.x == 0) flags[ti] = (acc[0] * 10 < n * 9) ? 1 : 0;
}

__global__ __launch_bounds__(256) void mask_bias_kernel(const uint32_t* __restrict__ raw,
                                                        float* __restrict__ mbias, int count) {
  int inspect = count >> 2; if (inspect > 256) inspect = 256;
  bool ok_i32 = true, ok_f32 = true, ok_bf16 = true;
  #pragma unroll 1
  for (int w = 0; w < inspect; ++w) {
    uint32_t v = raw[w];
    if (v > 1u) ok_i32 = false;
    if (!(v == 0u || v == 0x3F800000u)) ok_f32 = false;
    uint32_t lo = v & 0xFFFFu, hi = v >> 16;
    if (!((lo == 0u || lo == 0x3F80u) && (hi == 0u || hi == 0x3F80u))) ok_bf16 = false;
  }
  int idx = blockIdx.x * 256 + threadIdx.x;
  if (idx < count) {
    bool on;
    if (ok_i32 || ok_f32) on = raw[idx] != 0u;
    else if (ok_bf16)     on = ((const uint16_t*)raw)[idx] != 0u;
    else                  on = ((const uint8_t*)raw)[idx] != 0u;
    mbias[idx] = on ? 0.0f : -1e30f;
  }
}

// qkv = x @ Wqkv + bqkv ; q linear, k PERMUTED within-row ((c&15)*8 + c>>4) so
// gat_main's frag gather becomes one bf16x8 load, v TRANSPOSED (vT[c][j]) so
// the node phase reads contiguous bf16x8.
__global__ __launch_bounds__(128) void qkv_kernel(const void* __restrict__ xp,
                                                  const void* __restrict__ Wp,
                                                  const void* __restrict__ bp,
                                                  const int* __restrict__ flags,
                                                  uint16_t* __restrict__ qf,
                                                  uint16_t* __restrict__ kf,
                                                  uint16_t* __restrict__ vf) {
  const int f_x = flags[0], f_W = flags[2], f_b = flags[3];
  const int row = blockIdx.x;
  const int t = threadIdx.x;
  __shared__ float xs[HD];
  xs[t] = f_x ? ((const float*)xp)[row * HD + t] : bf2f(((const uint16_t*)xp)[row * HD + t]);
  __syncthreads();
  float aq = 0.f, ak = 0.f, av = 0.f;
  if (f_W) {
    const float* W = (const float*)Wp;
    #pragma unroll 4
    for (int kk = 0; kk < HD; ++kk) {
      float xv = xs[kk]; const float* wr = W + kk * 384;
      aq = fmaf(xv, wr[t], aq);
      ak = fmaf(xv, wr[128 + t], ak);
      av = fmaf(xv, wr[256 + t], av);
    }
  } else {
    const uint16_t* W = (const uint16_t*)Wp;
    #pragma unroll 4
    for (int kk = 0; kk < HD; ++kk) {
      float xv = xs[kk]; const uint16_t* wr = W + kk * 384;
      aq = fmaf(xv, bf2f(wr[t]), aq);
      ak = fmaf(xv, bf2f(wr[128 + t]), ak);
      av = fmaf(xv, bf2f(wr[256 + t]), av);
    }
  }
  float bq = f_b ? ((const float*)bp)[t]       : bf2f(((const uint16_t*)bp)[t]);
  float bk = f_b ? ((const float*)bp)[128 + t] : bf2f(((const uint16_t*)bp)[128 + t]);
  float bv = f_b ? ((const float*)bp)[256 + t] : bf2f(((const uint16_t*)bp)[256 + t]);
  qf[row * HD + t] = f2bf(aq + bq);
  kf[row * HD + ((t & 15) << 3) + (t >> 4)] = f2bf(ak + bk);
  vf[((size_t)((row >> 9) * HD + t)) * NN + (row & (NN - 1))] = f2bf(av + bv);
}

// One block per (b,i); 8 waves (512 thr), wave w owns bands {w, w+8, w+16, w+24}
// end-to-end (barrier-free j-loop). MFMA 16x16x32 bf16 for both GEMMs; logits
// computed by a 5th "head-indicator" B2 tile (B[k][h] = (k>>4==h)); softmax is
// per-wave-per-head (8 waves = 8 heads) with shuffle reductions; node phase
// reads transposed vT with vector loads. LDS = 80640 B -> 2 blocks/CU ->
// 4 waves/SIMD (double previous occupancy).
__global__ __launch_bounds__(512, 4) void gat_main_kernel(
    const void* __restrict__ eap,
    const void* __restrict__ Wep,  const void* __restrict__ bep,
    const void* __restrict__ Wnop, const void* __restrict__ bnop,
    const void* __restrict__ Weop, const void* __restrict__ beop,
    const int* __restrict__ flags,
    const uint16_t* __restrict__ qf, const uint16_t* __restrict__ kf,
    const uint16_t* __restrict__ vf, const float* __restrict__ mbias,
    float* __restrict__ node_out, float* __restrict__ edge_out) {
  const int tid = threadIdx.x;
  const int w = tid >> 6, lane = tid & 63;
  const int l15 = lane & 15, quad = lane >> 4;
  const int bb = blockIdx.x >> 9;
  const int i  = blockIdx.x & (NN - 1);
  const int f_ea = flags[1], f_We = flags[4], f_be = flags[5];
  const int f_Wno = flags[6], f_bno = flags[7], f_Weo = flags[8], f_beo = flags[9];

  // Frag-ready weight layouts: [tile][kstep][lane][8] (ds_read_b128/lane).
  __shared__ __align__(16) uint16_t B1f[8 * 2 * 64 * 8];   // We*q          16 KB
  __shared__ __align__(16) uint16_t B2f[5 * 4 * 64 * 8];   // Weo + sumtile 20 KB
  __shared__ __align__(16) uint16_t raw_s[8 * 16 * 132];   // per-wave, pad 132 (conflict-free) 33 KB
  __shared__ __align__(16) uint16_t att_s[8 * NN];         // [h][j]  8 KB
  __shared__ __align__(16) float q_s[HD];
  __shared__ __align__(16) float beq_s[HD];
  __shared__ __align__(16) float beo_s[64];
  __shared__ __align__(16) float node_s[HD];

  if (tid < HD) q_s[tid] = bf2f(qf[(bb * NN + i) * HD + tid]);
  if (tid >= 128 && tid < 192) {
    int c = tid - 128;
    beo_s[c] = f_beo ? ((const float*)beop)[c] : bf2f(((const uint16_t*)beop)[c]);
  }
  __syncthreads();

  if (tid < HD) {
    float b = f_be ? ((const float*)bep)[tid] : bf2f(((const uint16_t*)bep)[tid]);
    beq_s[tid] = b * q_s[tid];
  }
  // B1 frags: element = We[k][c] * q[c]; slot = t*128 + s*64 + ln.
  for (int slot = tid; slot < 1024; slot += 512) {
    const int t = slot >> 7, s = (slot >> 6) & 1, ln = slot & 63;
    const int c = t * 16 + (ln & 15);
    const int k0 = s * 32 + (ln >> 4) * 8;
    const float qc = q_s[c];
    bf16x8 fr;
    if (f_We) {
      const float* W = (const float*)Wep;
      #pragma unroll
      for (int e = 0; e < 8; ++e) fr[e] = (short)f2bf(W[(k0 + e) * HD + c] * qc);
    } else {
      const uint16_t* W = (const uint16_t*)Wep;
      #pragma unroll
      for (int e = 0; e < 8; ++e) fr[e] = (short)f2bf(bf2f(W[(k0 + e) * HD + c]) * qc);
    }
    *(bf16x8*)&B1f[slot * 8] = fr;
  }
  // B2 frags: tiles 0..3 = Weo[k][c]; tile 4 = head-sum indicator (k>>4 == h).
  for (int slot = tid; slot < 1280; slot += 512) {
    const int t2 = slot >> 8, s = (slot >> 6) & 3, ln = slot & 63;
    bf16x8 fr;
    if (t2 == 4) {
      const int head = s * 2 + ((ln >> 5) & 1);          // (s*32+quad*8+e)>>4
      const short v = ((ln & 15) == head) ? (short)0x3F80 : (short)0;
      #pragma unroll
      for (int e = 0; e < 8; ++e) fr[e] = v;
    } else {
      const int c = t2 * 16 + (ln & 15);
      const int k0 = s * 32 + ((ln >> 4) & 3) * 8;
      if (f_Weo) {
        const float* W = (const float*)Weop;
        #pragma unroll
        for (int e = 0; e < 8; ++e) fr[e] = (short)f2bf(W[(k0 + e) * 64 + c]);
      } else {
        const uint16_t* W = (const uint16_t*)Weop;
        #pragma unroll
        for (int e = 0; e < 8; ++e) fr[e] = (short)W[(k0 + e) * 64 + c];
      }
    }
    *(bf16x8*)&B2f[slot * 8] = fr;
  }
  __syncthreads();

  const size_t io_base = (size_t)(bb * NN + i) * NN * 64;   // elements
  const uint16_t* kperm = kf + (size_t)bb * NN * HD;        // permuted rows
  const float* mrow = mbias + bb * NN;
  uint16_t* rws = raw_s + w * (16 * 132);

  for (int band = w; band < 32; band += 8) {
    const int j0 = band * 16;
    // mask bias for this quad's 4 rows (vector load, issue early)
    const float4 mr = *(const float4*)(mrow + j0 + quad * 4);
    // k fragments: one bf16x8 per row gives k[jr][t*16+l15] for t=0..7
    bf16x8 k8[4];
    #pragma unroll
    for (int r = 0; r < 4; ++r)
      k8[r] = *(const bf16x8*)(kperm + (size_t)(j0 + quad * 4 + r) * HD + l15 * 8);

    // ---- A1 fragments straight from global edge_attr ----
    bf16x8 A1[2];
    if (f_ea) {
      const float* ea = (const float*)eap + io_base + (size_t)(j0 + l15) * 64 + quad * 8;
      #pragma unroll
      for (int s = 0; s < 2; ++s) {
        float4 u0 = *(const float4*)(ea + s * 32);
        float4 u1 = *(const float4*)(ea + s * 32 + 4);
        bf16x8 a;
        a[0] = (short)f2bf(u0.x); a[1] = (short)f2bf(u0.y);
        a[2] = (short)f2bf(u0.z); a[3] = (short)f2bf(u0.w);
        a[4] = (short)f2bf(u1.x); a[5] = (short)f2bf(u1.y);
        a[6] = (short)f2bf(u1.z); a[7] = (short)f2bf(u1.w);
        A1[s] = a;
      }
    } else {
      const uint16_t* ea = (const uint16_t*)eap + io_base + (size_t)(j0 + l15) * 64 + quad * 8;
      A1[0] = *(const bf16x8*)(ea);
      A1[1] = *(const bf16x8*)(ea + 32);
    }

    // ---- GEMM1 (e_q = ea @ (We*q) + be*q) fused with raw = k .* e_q ----
    #pragma unroll
    for (int t = 0; t < 8; ++t) {
      const float bv = beq_s[t * 16 + l15];
      f32x4 a = {bv, bv, bv, bv};
      a = __builtin_amdgcn_mfma_f32_16x16x32_bf16(
            A1[0], *(const bf16x8*)&B1f[(t * 2 + 0) * 512 + lane * 8], a, 0, 0, 0);
      a = __builtin_amdgcn_mfma_f32_16x16x32_bf16(
            A1[1], *(const bf16x8*)&B1f[(t * 2 + 1) * 512 + lane * 8], a, 0, 0, 0);
      #pragma unroll
      for (int r = 0; r < 4; ++r)
        rws[(quad * 4 + r) * 132 + t * 16 + l15] =
            f2bf(a[r] * bf2f((unsigned short)k8[r][t]));
    }

    // ---- A2 frags from per-wave LDS round trip (in-order within wave) ----
    bf16x8 A2[4];
    #pragma unroll
    for (int s = 0; s < 4; ++s)
      A2[s] = *(const bf16x8*)&rws[l15 * 132 + s * 32 + quad * 8];

    // ---- logits via indicator tile: D[jr][h] = sum_d raw[jr][h*16+d] ----
    {
      f32x4 aL = {0.f, 0.f, 0.f, 0.f};
      #pragma unroll
      for (int s = 0; s < 4; ++s)
        aL = __builtin_amdgcn_mfma_f32_16x16x32_bf16(
               A2[s], *(const bf16x8*)&B2f[(16 + s) * 512 + lane * 8], aL, 0, 0, 0);
      if (l15 < 8) {
        att_s[l15 * NN + (j0 + quad * 4 + 0)] = f2bf(aL[0] * 0.25f + mr.x);
        att_s[l15 * NN + (j0 + quad * 4 + 1)] = f2bf(aL[1] * 0.25f + mr.y);
        att_s[l15 * NN + (j0 + quad * 4 + 2)] = f2bf(aL[2] * 0.25f + mr.z);
        att_s[l15 * NN + (j0 + quad * 4 + 3)] = f2bf(aL[3] * 0.25f + mr.w);
      }
    }

    // ---- GEMM2: edge_out = raw @ Weo + beo ----
    #pragma unroll
    for (int t2 = 0; t2 < 4; ++t2) {
      const float bv = beo_s[t2 * 16 + l15];
      f32x4 a2 = {bv, bv, bv, bv};
      #pragma unroll
      for (int s = 0; s < 4; ++s)
        a2 = __builtin_amdgcn_mfma_f32_16x16x32_bf16(
               A2[s], *(const bf16x8*)&B2f[(t2 * 4 + s) * 512 + lane * 8], a2, 0, 0, 0);
      #pragma unroll
      for (int r = 0; r < 4; ++r)
        edge_out[io_base + (size_t)(j0 + quad * 4 + r) * 64 + t2 * 16 + l15] = a2[r];
    }
  }
  __syncthreads();

  // ---- softmax over j: wave w owns head w; shuffle reductions, no LDS scratch ----
  {
    float vals[8];
    float m = -3.4e38f;
    #pragma unroll
    for (int it = 0; it < 8; ++it)
      m = fmaxf(m, bf2f(att_s[w * NN + it * 64 + lane]));
    #pragma unroll
    for (int off = 32; off; off >>= 1) m = fmaxf(m, __shfl_xor(m, off));
    float ssum = 0.f;
    #pragma unroll
    for (int it = 0; it < 8; ++it) {
      float v = __expf(bf2f(att_s[w * NN + it * 64 + lane]) - m);
      vals[it] = v; ssum += v;
    }
    #pragma unroll
    for (int off = 32; off; off >>= 1) ssum += __shfl_xor(ssum, off);
    const float inv = 1.0f / ssum;
    #pragma unroll
    for (int it = 0; it < 8; ++it)
      att_s[w * NN + it * 64 + lane] = f2bf(vals[it] * inv);
  }
  // no barrier needed: node phase of wave w consumes only head w (written above)

  // ---- node = att @ v : wave w -> cols w*16..w*16+15 (head w), quad = j-part ----
  {
    const int c = w * 16 + l15;
    const uint16_t* vb = vf + ((size_t)(bb * HD + c)) * NN + quad * 128;
    float acc = 0.f;
    #pragma unroll
    for (int u = 0; u < 16; ++u) {
      bf16x8 v8 = *(const bf16x8*)(vb + u * 8);
      bf16x8 a8 = *(const bf16x8*)&att_s[w * NN + quad * 128 + u * 8];
      #pragma unroll
      for (int e = 0; e < 8; ++e)
        acc = fmaf(bf2f((unsigned short)a8[e]), bf2f((unsigned short)v8[e]), acc);
    }
    acc += __shfl_xor(acc, 16);
    acc += __shfl_xor(acc, 32);
    if (quad == 0) node_s[c] = acc;
  }
  __syncthreads();

  // ---- node_out = node @ Wno + bno ----
  if (tid < HD) {
    float acc = f_bno ? ((const float*)bnop)[tid] : bf2f(((const uint16_t*)bnop)[tid]);
    if (f_Wno) {
      const float* W = (const float*)Wnop;
      #pragma unroll 4
      for (int kk = 0; kk < HD; ++kk) acc = fmaf(node_s[kk], W[kk * HD + tid], acc);
    } else {
      const uint16_t* W = (const uint16_t*)Wnop;
      #pragma unroll 4
      for (int kk = 0; kk < HD; ++kk) acc = fmaf(node_s[kk], bf2f(W[kk * HD + tid]), acc);
    }
    node_out[(bb * NN + i) * HD + tid] = acc;
  }
}

extern "C" void kernel_launch(void* const* d_in, const int* in_sizes, int n_in,
                              void* d_out, int out_size, void* d_ws, size_t ws_size,
                              hipStream_t stream) {
  const int b = in_sizes[0] / (NN * HD);   // = 2
  const int rows = b * NN;                 // = 1024

  int*   flags = (int*)d_ws;                                        // 16 ints
  float* mbias = (float*)((char*)d_ws + 64);                        // rows floats
  uint16_t* qf = (uint16_t*)((char*)d_ws + 64 + 4096);
  uint16_t* kf = qf + (size_t)rows * HD;
  uint16_t* vf = kf + (size_t)rows * HD;                            // transposed [b][c][j]

  float* node_out = (float*)d_out;
  float* edge_out = node_out + (size_t)rows * HD;

  DetectArgs da;
  const int float_idx[10] = {0, 1, 3, 4, 5, 6, 7, 8, 9, 10};
  for (int t = 0; t < 10; ++t) {
    da.p[t] = (const uint16_t*)d_in[float_idx[t]];
    da.n[t] = in_sizes[float_idx[t]];
  }

  detect_kernel<<<10, 256, 0, stream>>>(da, flags);
  mask_bias_kernel<<<(rows + 255) / 256, 256, 0, stream>>>((const uint32_t*)d_in[2], mbias, rows);
  qkv_kernel<<<rows, 128, 0, stream>>>(d_in[0], d_in[3], d_in[4], flags, qf, kf, vf);
  gat_main_kernel<<<rows, 512, 0, stream>>>(d_in[1], d_in[5], d_in[6], d_in[7], d_in[8],
                                            d_in[9], d_in[10], flags,
                                            qf, kf, vf, mbias, node_out, edge_out);
}

// Round 2
// 355.005 us; speedup vs baseline: 1.4705x; 1.3493x over previous
//
#include <hip/hip_runtime.h>
#include <hip/hip_bf16.h>
#include <stdint.h>

#define NN 512
#define HD 128

typedef __attribute__((ext_vector_type(8))) short bf16x8;
typedef __attribute__((ext_vector_type(4))) float f32x4;

static __device__ __forceinline__ float bf2f(unsigned short u) {
  union { uint32_t u32; float f; } cv; cv.u32 = ((uint32_t)u) << 16; return cv.f;
}
static __device__ __forceinline__ unsigned short f2bf(float f) {
  union { float f; uint32_t u; } cv; cv.f = f;
  return (unsigned short)((cv.u + 0x7FFFu + ((cv.u >> 16) & 1u)) >> 16);
}

struct DetectArgs { const uint16_t* p[10]; int n[10]; };

// Per-tensor dtype sniffing (flags[ti]=1 -> fp32, 0 -> bf16).
__global__ __launch_bounds__(256) void detect_kernel(DetectArgs a, int* __restrict__ flags) {
  __shared__ int acc[256];
  const int ti = blockIdx.x;
  int n = a.n[ti]; if (n > 2048) n = 2048;
  int g = 0;
  for (int w = threadIdx.x; w < n; w += 256) {
    uint16_t v = a.p[ti][w];
    int e = (v >> 7) & 0xFF;
    g += (v == 0u || (e >= 90 && e <= 133)) ? 1 : 0;
  }
  acc[threadIdx.x] = g;
  __syncthreads();
  for (int s = 128; s > 0; s >>= 1) {
    if (threadIdx.x < s) acc[threadIdx.x] += acc[threadIdx.x + s];
    __syncthreads();
  }
  if (threadIdx.x == 0) flags[ti] = (acc[0] * 10 < n * 9) ? 1 : 0;
}

__global__ __launch_bounds__(256) void mask_bias_kernel(const uint32_t* __restrict__ raw,
                                                        float* __restrict__ mbias, int count) {
  int inspect = count >> 2; if (inspect > 256) inspect = 256;
  bool ok_i32 = true, ok_f32 = true, ok_bf16 = true;
  #pragma unroll 1
  for (int w = 0; w < inspect; ++w) {
    uint32_t v = raw[w];
    if (v > 1u) ok_i32 = false;
    if (!(v == 0u || v == 0x3F800000u)) ok_f32 = false;
    uint32_t lo = v & 0xFFFFu, hi = v >> 16;
    if (!((lo == 0u || lo == 0x3F80u) && (hi == 0u || hi == 0x3F80u))) ok_bf16 = false;
  }
  int idx = blockIdx.x * 256 + threadIdx.x;
  if (idx < count) {
    bool on;
    if (ok_i32 || ok_f32) on = raw[idx] != 0u;
    else if (ok_bf16)     on = ((const uint16_t*)raw)[idx] != 0u;
    else                  on = ((const uint8_t*)raw)[idx] != 0u;
    mbias[idx] = on ? 0.0f : -1e30f;
  }
}

// qkv = x @ Wqkv + bqkv ; q linear, k PERMUTED within-row ((c&15)*8 + c>>4) so
// gat_main's frag gather is one bf16x8 load, v TRANSPOSED (vT[c][j]) so the
// node phase reads contiguous bf16x8.
__global__ __launch_bounds__(128) void qkv_kernel(const void* __restrict__ xp,
                                                  const void* __restrict__ Wp,
                                                  const void* __restrict__ bp,
                                                  const int* __restrict__ flags,
                                                  uint16_t* __restrict__ qf,
                                                  uint16_t* __restrict__ kf,
                                                  uint16_t* __restrict__ vf) {
  const int f_x = flags[0], f_W = flags[2], f_b = flags[3];
  const int row = blockIdx.x;
  const int t = threadIdx.x;
  __shared__ float xs[HD];
  xs[t] = f_x ? ((const float*)xp)[row * HD + t] : bf2f(((const uint16_t*)xp)[row * HD + t]);
  __syncthreads();
  float aq = 0.f, ak = 0.f, av = 0.f;
  if (f_W) {
    const float* W = (const float*)Wp;
    #pragma unroll 4
    for (int kk = 0; kk < HD; ++kk) {
      float xv = xs[kk]; const float* wr = W + kk * 384;
      aq = fmaf(xv, wr[t], aq);
      ak = fmaf(xv, wr[128 + t], ak);
      av = fmaf(xv, wr[256 + t], av);
    }
  } else {
    const uint16_t* W = (const uint16_t*)Wp;
    #pragma unroll 4
    for (int kk = 0; kk < HD; ++kk) {
      float xv = xs[kk]; const uint16_t* wr = W + kk * 384;
      aq = fmaf(xv, bf2f(wr[t]), aq);
      ak = fmaf(xv, bf2f(wr[128 + t]), ak);
      av = fmaf(xv, bf2f(wr[256 + t]), av);
    }
  }
  float bq = f_b ? ((const float*)bp)[t]       : bf2f(((const uint16_t*)bp)[t]);
  float bk = f_b ? ((const float*)bp)[128 + t] : bf2f(((const uint16_t*)bp)[128 + t]);
  float bv = f_b ? ((const float*)bp)[256 + t] : bf2f(((const uint16_t*)bp)[256 + t]);
  qf[row * HD + t] = f2bf(aq + bq);
  kf[row * HD + ((t & 15) << 3) + (t >> 4)] = f2bf(ak + bk);
  vf[((size_t)((row >> 9) * HD + t)) * NN + (row & (NN - 1))] = f2bf(av + bv);
}

// One block per (b,i); 8 waves (512 thr), wave w owns bands {w, w+8, w+16, w+24}
// end-to-end (barrier-free j-loop). Logits via 5th "head-indicator" B2 tile.
// R2: edge_out written as full contiguous 1KB-per-instruction wave stores via
// an f32 LDS staging transpose (kills partial-line RFO amplification seen in
// R1: WRITE 331MB vs 134MB ideal, FETCH 410MB); ea loads software-pipelined
// one band ahead; nontemporal hints on the two streaming tensors.
__global__ __launch_bounds__(512, 4) void gat_main_kernel(
    const void* __restrict__ eap,
    const void* __restrict__ Wep,  const void* __restrict__ bep,
    const void* __restrict__ Wnop, const void* __restrict__ bnop,
    const void* __restrict__ Weop, const void* __restrict__ beop,
    const int* __restrict__ flags,
    const uint16_t* __restrict__ qf, const uint16_t* __restrict__ kf,
    const uint16_t* __restrict__ vf, const float* __restrict__ mbias,
    float* __restrict__ node_out, float* __restrict__ edge_out) {
  const int tid = threadIdx.x;
  const int w = tid >> 6, lane = tid & 63;
  const int l15 = lane & 15, quad = lane >> 4;
  const int bb = blockIdx.x >> 9;
  const int i  = blockIdx.x & (NN - 1);
  const int f_ea = flags[1], f_We = flags[4], f_be = flags[5];
  const int f_Wno = flags[6], f_bno = flags[7], f_Weo = flags[8], f_beo = flags[9];

  // Frag-ready weight layouts: [tile][kstep][lane][8] (ds_read_b128/lane).
  __shared__ __align__(16) uint16_t B1f[8 * 2 * 64 * 8];   // We*q          16 KB
  __shared__ __align__(16) uint16_t B2f[5 * 4 * 64 * 8];   // Weo + sumtile 20 KB
  // per-wave scratch: bf16 raw tile (stride 136 u16 = 272 B/row) REUSED as
  // f32 edge_out staging (stride 68 f32 = 272 B/row, 16B-aligned rows). 34 KB
  __shared__ __align__(16) uint16_t raw_s[8 * 16 * 136];
  __shared__ __align__(16) uint16_t att_s[8 * NN];         // [h][j]  8 KB
  __shared__ __align__(16) float q_s[HD];
  __shared__ __align__(16) float beq_s[HD];
  __shared__ __align__(16) float beo_s[64];
  __shared__ __align__(16) float node_s[HD];

  if (tid < HD) q_s[tid] = bf2f(qf[(bb * NN + i) * HD + tid]);
  if (tid >= 128 && tid < 192) {
    int c = tid - 128;
    beo_s[c] = f_beo ? ((const float*)beop)[c] : bf2f(((const uint16_t*)beop)[c]);
  }
  __syncthreads();

  if (tid < HD) {
    float b = f_be ? ((const float*)bep)[tid] : bf2f(((const uint16_t*)bep)[tid]);
    beq_s[tid] = b * q_s[tid];
  }
  // B1 frags: element = We[k][c] * q[c]; slot = t*128 + s*64 + ln.
  for (int slot = tid; slot < 1024; slot += 512) {
    const int t = slot >> 7, s = (slot >> 6) & 1, ln = slot & 63;
    const int c = t * 16 + (ln & 15);
    const int k0 = s * 32 + (ln >> 4) * 8;
    const float qc = q_s[c];
    bf16x8 fr;
    if (f_We) {
      const float* W = (const float*)Wep;
      #pragma unroll
      for (int e = 0; e < 8; ++e) fr[e] = (short)f2bf(W[(k0 + e) * HD + c] * qc);
    } else {
      const uint16_t* W = (const uint16_t*)Wep;
      #pragma unroll
      for (int e = 0; e < 8; ++e) fr[e] = (short)f2bf(bf2f(W[(k0 + e) * HD + c]) * qc);
    }
    *(bf16x8*)&B1f[slot * 8] = fr;
  }
  // B2 frags: tiles 0..3 = Weo[k][c]; tile 4 = head-sum indicator (k>>4 == h).
  for (int slot = tid; slot < 1280; slot += 512) {
    const int t2 = slot >> 8, s = (slot >> 6) & 3, ln = slot & 63;
    bf16x8 fr;
    if (t2 == 4) {
      const int head = s * 2 + ((ln >> 5) & 1);          // (s*32+quad*8+e)>>4
      const short v = ((ln & 15) == head) ? (short)0x3F80 : (short)0;
      #pragma unroll
      for (int e = 0; e < 8; ++e) fr[e] = v;
    } else {
      const int c = t2 * 16 + (ln & 15);
      const int k0 = s * 32 + ((ln >> 4) & 3) * 8;
      if (f_Weo) {
        const float* W = (const float*)Weop;
        #pragma unroll
        for (int e = 0; e < 8; ++e) fr[e] = (short)f2bf(W[(k0 + e) * 64 + c]);
      } else {
        const uint16_t* W = (const uint16_t*)Weop;
        #pragma unroll
        for (int e = 0; e < 8; ++e) fr[e] = (short)W[(k0 + e) * 64 + c];
      }
    }
    *(bf16x8*)&B2f[slot * 8] = fr;
  }
  __syncthreads();

  const size_t io_base = (size_t)(bb * NN + i) * NN * 64;   // elements
  const uint16_t* kperm = kf + (size_t)bb * NN * HD;        // permuted rows
  const float* mrow = mbias + bb * NN;
  uint16_t* rws = raw_s + w * (16 * 136);
  float*    fws = (float*)rws;                               // stride 68 f32/row

  // Band body: everything after the A1 fragments are in registers.
  auto body = [&](int band, const bf16x8* A1) {
    const int j0 = band * 16;
    // k frags + mask bias (L2-resident, short latency; issue up front)
    const f32x4 mr = *(const f32x4*)(mrow + j0 + quad * 4);
    bf16x8 k8[4];
    #pragma unroll
    for (int r = 0; r < 4; ++r)
      k8[r] = *(const bf16x8*)(kperm + (size_t)(j0 + quad * 4 + r) * HD + l15 * 8);

    // ---- GEMM1 (e_q = ea @ (We*q) + be*q) fused with raw = k .* e_q ----
    #pragma unroll
    for (int t = 0; t < 8; ++t) {
      const float bv = beq_s[t * 16 + l15];
      f32x4 a = {bv, bv, bv, bv};
      a = __builtin_amdgcn_mfma_f32_16x16x32_bf16(
            A1[0], *(const bf16x8*)&B1f[(t * 2 + 0) * 512 + lane * 8], a, 0, 0, 0);
      a = __builtin_amdgcn_mfma_f32_16x16x32_bf16(
            A1[1], *(const bf16x8*)&B1f[(t * 2 + 1) * 512 + lane * 8], a, 0, 0, 0);
      #pragma unroll
      for (int r = 0; r < 4; ++r)
        rws[(quad * 4 + r) * 136 + t * 16 + l15] =
            f2bf(a[r] * bf2f((unsigned short)k8[r][t]));
    }

    // ---- A2 frags from per-wave LDS round trip ----
    bf16x8 A2[4];
    #pragma unroll
    for (int s = 0; s < 4; ++s)
      A2[s] = *(const bf16x8*)&rws[l15 * 136 + s * 32 + quad * 8];

    // ---- logits via indicator tile: D[jr][h] = sum_d raw[jr][h*16+d] ----
    {
      f32x4 aL = {0.f, 0.f, 0.f, 0.f};
      #pragma unroll
      for (int s = 0; s < 4; ++s)
        aL = __builtin_amdgcn_mfma_f32_16x16x32_bf16(
               A2[s], *(const bf16x8*)&B2f[(16 + s) * 512 + lane * 8], aL, 0, 0, 0);
      if (l15 < 8) {
        att_s[l15 * NN + (j0 + quad * 4 + 0)] = f2bf(aL[0] * 0.25f + mr[0]);
        att_s[l15 * NN + (j0 + quad * 4 + 1)] = f2bf(aL[1] * 0.25f + mr[1]);
        att_s[l15 * NN + (j0 + quad * 4 + 2)] = f2bf(aL[2] * 0.25f + mr[2]);
        att_s[l15 * NN + (j0 + quad * 4 + 3)] = f2bf(aL[3] * 0.25f + mr[3]);
      }
    }

    // ---- GEMM2: edge_out = raw @ Weo + beo -> f32 LDS staging ----
    #pragma unroll
    for (int t2 = 0; t2 < 4; ++t2) {
      const float bv = beo_s[t2 * 16 + l15];
      f32x4 a2 = {bv, bv, bv, bv};
      #pragma unroll
      for (int s = 0; s < 4; ++s)
        a2 = __builtin_amdgcn_mfma_f32_16x16x32_bf16(
               A2[s], *(const bf16x8*)&B2f[(t2 * 4 + s) * 512 + lane * 8], a2, 0, 0, 0);
      #pragma unroll
      for (int r = 0; r < 4; ++r)
        fws[(quad * 4 + r) * 68 + t2 * 16 + l15] = a2[r];
    }

    // ---- write out: one wave instruction = 4 complete rows = 1024 contig B ----
    float* eo = edge_out + io_base + (size_t)j0 * 64;
    #pragma unroll
    for (int u = 0; u < 4; ++u) {
      const int jr = u * 4 + quad;
      f32x4 vv = *(const f32x4*)&fws[jr * 68 + l15 * 4];
      __builtin_nontemporal_store(vv, (f32x4*)(eo + jr * 64) + l15);
    }
  };

  if (f_ea) {
    // fp32 edge_attr: pipeline raw f32x4 loads one band ahead, convert late.
    f32x4 ef[4];
    {
      const float* ea = (const float*)eap + io_base + (size_t)(w * 16 + l15) * 64 + quad * 8;
      ef[0] = __builtin_nontemporal_load((const f32x4*)ea);
      ef[1] = __builtin_nontemporal_load((const f32x4*)(ea + 4));
      ef[2] = __builtin_nontemporal_load((const f32x4*)(ea + 32));
      ef[3] = __builtin_nontemporal_load((const f32x4*)(ea + 36));
    }
    #pragma unroll
    for (int bi = 0; bi < 4; ++bi) {
      const int band = w + bi * 8;
      f32x4 efn[4];
      if (bi < 3) {
        const float* ea = (const float*)eap + io_base + (size_t)((band + 8) * 16 + l15) * 64 + quad * 8;
        efn[0] = __builtin_nontemporal_load((const f32x4*)ea);
        efn[1] = __builtin_nontemporal_load((const f32x4*)(ea + 4));
        efn[2] = __builtin_nontemporal_load((const f32x4*)(ea + 32));
        efn[3] = __builtin_nontemporal_load((const f32x4*)(ea + 36));
      }
      bf16x8 A1[2];
      #pragma unroll
      for (int s = 0; s < 2; ++s) {
        bf16x8 a;
        #pragma unroll
        for (int e = 0; e < 4; ++e) {
          a[e]     = (short)f2bf(ef[2 * s][e]);
          a[e + 4] = (short)f2bf(ef[2 * s + 1][e]);
        }
        A1[s] = a;
      }
      body(band, A1);
      if (bi < 3) {
        #pragma unroll
        for (int s = 0; s < 4; ++s) ef[s] = efn[s];
      }
    }
  } else {
    // bf16 edge_attr path
    bf16x8 eb[2];
    {
      const uint16_t* ea = (const uint16_t*)eap + io_base + (size_t)(w * 16 + l15) * 64 + quad * 8;
      eb[0] = __builtin_nontemporal_load((const bf16x8*)ea);
      eb[1] = __builtin_nontemporal_load((const bf16x8*)(ea + 32));
    }
    #pragma unroll
    for (int bi = 0; bi < 4; ++bi) {
      const int band = w + bi * 8;
      bf16x8 ebn[2];
      if (bi < 3) {
        const uint16_t* ea = (const uint16_t*)eap + io_base + (size_t)((band + 8) * 16 + l15) * 64 + quad * 8;
        ebn[0] = __builtin_nontemporal_load((const bf16x8*)ea);
        ebn[1] = __builtin_nontemporal_load((const bf16x8*)(ea + 32));
      }
      body(band, eb);
      if (bi < 3) { eb[0] = ebn[0]; eb[1] = ebn[1]; }
    }
  }
  __syncthreads();

  // ---- softmax over j: wave w owns head w; shuffle reductions ----
  {
    float vals[8];
    float m = -3.4e38f;
    #pragma unroll
    for (int it = 0; it < 8; ++it)
      m = fmaxf(m, bf2f(att_s[w * NN + it * 64 + lane]));
    #pragma unroll
    for (int off = 32; off; off >>= 1) m = fmaxf(m, __shfl_xor(m, off));
    float ssum = 0.f;
    #pragma unroll
    for (int it = 0; it < 8; ++it) {
      float v = __expf(bf2f(att_s[w * NN + it * 64 + lane]) - m);
      vals[it] = v; ssum += v;
    }
    #pragma unroll
    for (int off = 32; off; off >>= 1) ssum += __shfl_xor(ssum, off);
    const float inv = 1.0f / ssum;
    #pragma unroll
    for (int it = 0; it < 8; ++it)
      att_s[w * NN + it * 64 + lane] = f2bf(vals[it] * inv);
  }
  // no barrier: node phase of wave w consumes only head w (written above)

  // ---- node = att @ v : wave w -> cols w*16..w*16+15 (head w) ----
  {
    const int c = w * 16 + l15;
    const uint16_t* vb = vf + ((size_t)(bb * HD + c)) * NN + quad * 128;
    float acc = 0.f;
    #pragma unroll
    for (int u = 0; u < 16; ++u) {
      bf16x8 v8 = *(const bf16x8*)(vb + u * 8);
      bf16x8 a8 = *(const bf16x8*)&att_s[w * NN + quad * 128 + u * 8];
      #pragma unroll
      for (int e = 0; e < 8; ++e)
        acc = fmaf(bf2f((unsigned short)a8[e]), bf2f((unsigned short)v8[e]), acc);
    }
    acc += __shfl_xor(acc, 16);
    acc += __shfl_xor(acc, 32);
    if (quad == 0) node_s[c] = acc;
  }
  __syncthreads();

  // ---- node_out = node @ Wno + bno ----
  if (tid < HD) {
    float acc = f_bno ? ((const float*)bnop)[tid] : bf2f(((const uint16_t*)bnop)[tid]);
    if (f_Wno) {
      const float* W = (const float*)Wnop;
      #pragma unroll 4
      for (int kk = 0; kk < HD; ++kk) acc = fmaf(node_s[kk], W[kk * HD + tid], acc);
    } else {
      const uint16_t* W = (const uint16_t*)Wnop;
      #pragma unroll 4
      for (int kk = 0; kk < HD; ++kk) acc = fmaf(node_s[kk], bf2f(W[kk * HD + tid]), acc);
    }
    node_out[(bb * NN + i) * HD + tid] = acc;
  }
}

extern "C" void kernel_launch(void* const* d_in, const int* in_sizes, int n_in,
                              void* d_out, int out_size, void* d_ws, size_t ws_size,
                              hipStream_t stream) {
  const int b = in_sizes[0] / (NN * HD);   // = 2
  const int rows = b * NN;                 // = 1024

  int*   flags = (int*)d_ws;                                        // 16 ints
  float* mbias = (float*)((char*)d_ws + 64);                        // rows floats
  uint16_t* qf = (uint16_t*)((char*)d_ws + 64 + 4096);
  uint16_t* kf = qf + (size_t)rows * HD;
  uint16_t* vf = kf + (size_t)rows * HD;                            // transposed [b][c][j]

  float* node_out = (float*)d_out;
  float* edge_out = node_out + (size_t)rows * HD;

  DetectArgs da;
  const int float_idx[10] = {0, 1, 3, 4, 5, 6, 7, 8, 9, 10};
  for (int t = 0; t < 10; ++t) {
    da.p[t] = (const uint16_t*)d_in[float_idx[t]];
    da.n[t] = in_sizes[float_idx[t]];
  }

  detect_kernel<<<10, 256, 0, stream>>>(da, flags);
  mask_bias_kernel<<<(rows + 255) / 256, 256, 0, stream>>>((const uint32_t*)d_in[2], mbias, rows);
  qkv_kernel<<<rows, 128, 0, stream>>>(d_in[0], d_in[3], d_in[4], flags, qf, kf, vf);
  gat_main_kernel<<<rows, 512, 0, stream>>>(d_in[1], d_in[5], d_in[6], d_in[7], d_in[8],
                                            d_in[9], d_in[10], flags,
                                            qf, kf, vf, mbias, node_out, edge_out);
}